// Round 1
// baseline (1609.255 us; speedup 1.0000x reference)
//
#include <hip/hip_runtime.h>
#include <hip/hip_bf16.h>
#include <math.h>

// ---------------------------------------------------------------------------
// GCN 3-layer + mean-pool + linear head + softmax, fp32.
// Inputs (in_sizes order): features[N,64], edge_index[2,E] (int32),
// batch[N] (int32, sorted), W1[64,64], b1[64], W2, b2, W3, b3,
// Wf[192,10], bf[10].  Output: softmax [128, 10] fp32.
// ---------------------------------------------------------------------------

#define F 64
#define NGRAPHS 128
#define NCLASSES 10
#define FCAT 192

// deg[i] = 1 (self loop)
__global__ void k_deg_init(float* __restrict__ deg, int n) {
    int i = blockIdx.x * blockDim.x + threadIdx.x;
    if (i < n) deg[i] = 1.0f;
}

// deg[col[e]] += 1
__global__ void k_deg_scatter(const int* __restrict__ col, float* __restrict__ deg, int E) {
    int e = blockIdx.x * blockDim.x + threadIdx.x;
    if (e < E) atomicAdd(&deg[col[e]], 1.0f);
}

// deg -> rsqrt(deg)  (deg >= 1 always, so no zero guard needed)
__global__ void k_rsqrt(float* __restrict__ d, int n) {
    int i = blockIdx.x * blockDim.x + threadIdx.x;
    if (i < n) d[i] = rsqrtf(d[i]);
}

// xw = x @ W ; agg = xw * dinv^2  (self-loop contribution pre-initialized)
// one wave (64 lanes) per row; W staged in LDS.
__global__ __launch_bounds__(256) void k_gemm_xw(
        const float* __restrict__ x, const float* __restrict__ W,
        const float* __restrict__ dinv,
        float* __restrict__ xw, float* __restrict__ agg, int n) {
    __shared__ float Wl[F * F];
    for (int i = threadIdx.x; i < F * F; i += 256) Wl[i] = W[i];
    __syncthreads();
    int r = blockIdx.x * 4 + (threadIdx.x >> 6);
    int f = threadIdx.x & 63;
    if (r >= n) return;
    const float* xr = x + (size_t)r * F;
    float acc = 0.0f;
#pragma unroll
    for (int k = 0; k < F; ++k) acc = fmaf(xr[k], Wl[k * F + f], acc);
    size_t o = (size_t)r * F + f;
    xw[o] = acc;
    float di = dinv[r];
    agg[o] = acc * di * di;
}

// agg[col[e]*64+f] += xw[row[e]*64+f] * dinv[row]*dinv[col]
__global__ void k_edge_scatter(const int* __restrict__ row, const int* __restrict__ col,
                               const float* __restrict__ dinv,
                               const float* __restrict__ xw, float* __restrict__ agg,
                               int E) {
    int idx = blockIdx.x * blockDim.x + threadIdx.x;
    int e = idx >> 6;
    if (e >= E) return;
    int f = idx & 63;
    int r = row[e], c = col[e];
    float nrm = dinv[r] * dinv[c];
    atomicAdd(&agg[(size_t)c * F + f], xw[(size_t)r * F + f] * nrm);
}

// x = relu(x + b)
__global__ void k_relu_bias(float* __restrict__ x, const float* __restrict__ b, int total) {
    int idx = blockIdx.x * blockDim.x + threadIdx.x;
    if (idx >= total) return;
    float v = x[idx] + b[idx & 63];
    x[idx] = v > 0.0f ? v : 0.0f;
}

// one block (192 threads) per graph; batch is sorted -> binary search bounds
__global__ __launch_bounds__(FCAT) void k_pool(
        const float* __restrict__ x1, const float* __restrict__ x2,
        const float* __restrict__ x3, const int* __restrict__ batch,
        int n, float* __restrict__ pooled) {
    int g = blockIdx.x;
    // lower_bound(g)
    int lo = 0, hi = n;
    while (lo < hi) { int m = (lo + hi) >> 1; if (batch[m] < g) lo = m + 1; else hi = m; }
    int s = lo;
    lo = s; hi = n;
    while (lo < hi) { int m = (lo + hi) >> 1; if (batch[m] < g + 1) lo = m + 1; else hi = m; }
    int e = lo;
    int f = threadIdx.x;              // 0..191
    const float* src = (f < 64) ? x1 : (f < 128) ? x2 : x3;
    int ff = f & 63;
    float sum = 0.0f;
    for (int i = s; i < e; ++i) sum += src[(size_t)i * F + ff];
    float cnt = (float)(e - s);
    pooled[g * FCAT + f] = sum / fmaxf(cnt, 1.0f);
}

// logits = pooled @ Wf + bf ; softmax; one thread per graph
__global__ void k_head(const float* __restrict__ pooled, const float* __restrict__ Wf,
                       const float* __restrict__ bf, float* __restrict__ out) {
    int g = blockIdx.x * blockDim.x + threadIdx.x;
    if (g >= NGRAPHS) return;
    float logit[NCLASSES];
#pragma unroll
    for (int c = 0; c < NCLASSES; ++c) logit[c] = bf[c];
    for (int k = 0; k < FCAT; ++k) {
        float p = pooled[g * FCAT + k];
#pragma unroll
        for (int c = 0; c < NCLASSES; ++c) logit[c] = fmaf(p, Wf[k * NCLASSES + c], logit[c]);
    }
    float mx = logit[0];
#pragma unroll
    for (int c = 1; c < NCLASSES; ++c) mx = fmaxf(mx, logit[c]);
    float s = 0.0f;
#pragma unroll
    for (int c = 0; c < NCLASSES; ++c) { logit[c] = expf(logit[c] - mx); s += logit[c]; }
    float inv = 1.0f / s;
#pragma unroll
    for (int c = 0; c < NCLASSES; ++c) out[g * NCLASSES + c] = logit[c] * inv;
}

extern "C" void kernel_launch(void* const* d_in, const int* in_sizes, int n_in,
                              void* d_out, int out_size, void* d_ws, size_t ws_size,
                              hipStream_t stream) {
    const float* features = (const float*)d_in[0];
    const int*   edge     = (const int*)d_in[1];
    const int*   batch    = (const int*)d_in[2];
    const float* W1 = (const float*)d_in[3]; const float* b1 = (const float*)d_in[4];
    const float* W2 = (const float*)d_in[5]; const float* b2 = (const float*)d_in[6];
    const float* W3 = (const float*)d_in[7]; const float* b3 = (const float*)d_in[8];
    const float* Wf = (const float*)d_in[9]; const float* bf = (const float*)d_in[10];
    float* out = (float*)d_out;

    const int n = in_sizes[0] / F;           // 100000
    const int E = in_sizes[1] / 2;           // 1600000
    const int* row = edge;                   // edge_index[0]
    const int* col = edge + E;               // edge_index[1]

    // workspace layout (floats)
    float* ws = (float*)d_ws;
    float* dinv   = ws;                      // [n]
    float* xw     = dinv + n;                // [n*64]
    float* x1     = xw + (size_t)n * F;      // [n*64]
    float* x2     = x1 + (size_t)n * F;      // [n*64]
    float* x3     = x2 + (size_t)n * F;      // [n*64]
    float* pooled = x3 + (size_t)n * F;      // [128*192]

    const int BT = 256;
    int gn   = (n + BT - 1) / BT;
    int gE   = (E + BT - 1) / BT;
    int gNF  = ((int)((size_t)n * F) + BT - 1) / BT;
    long long totEF = (long long)E * F;
    int gEF  = (int)((totEF + BT - 1) / BT);
    int gRow = (n + 3) / 4;

    // ---- normalization coefficients ----
    k_deg_init<<<gn, BT, 0, stream>>>(dinv, n);
    k_deg_scatter<<<gE, BT, 0, stream>>>(col, dinv, E);
    k_rsqrt<<<gn, BT, 0, stream>>>(dinv, n);

    // ---- layer 1 ----
    k_gemm_xw<<<gRow, BT, 0, stream>>>(features, W1, dinv, xw, x1, n);
    k_edge_scatter<<<gEF, BT, 0, stream>>>(row, col, dinv, xw, x1, E);
    k_relu_bias<<<gNF, BT, 0, stream>>>(x1, b1, n * F);

    // ---- layer 2 ----
    k_gemm_xw<<<gRow, BT, 0, stream>>>(x1, W2, dinv, xw, x2, n);
    k_edge_scatter<<<gEF, BT, 0, stream>>>(row, col, dinv, xw, x2, E);
    k_relu_bias<<<gNF, BT, 0, stream>>>(x2, b2, n * F);

    // ---- layer 3 ----
    k_gemm_xw<<<gRow, BT, 0, stream>>>(x2, W3, dinv, xw, x3, n);
    k_edge_scatter<<<gEF, BT, 0, stream>>>(row, col, dinv, xw, x3, E);
    k_relu_bias<<<gNF, BT, 0, stream>>>(x3, b3, n * F);

    // ---- pool + head ----
    k_pool<<<NGRAPHS, FCAT, 0, stream>>>(x1, x2, x3, batch, n, pooled);
    k_head<<<2, 64, 0, stream>>>(pooled, Wf, bf, out);
}

// Round 2
// 648.114 us; speedup vs baseline: 2.4830x; 2.4830x over previous
//
#include <hip/hip_runtime.h>
#include <hip/hip_bf16.h>
#include <math.h>

// ---------------------------------------------------------------------------
// GCN 3-layer + mean-pool + linear head + softmax, fp32.
// Strategy: build CSR (by dest col, self-loops inlined) once per launch,
// then per layer: GEMM (x@W) -> gather-aggregate (+bias+ReLU fused) ->
// per-layer split pooling. No f32 atomics on the feature buffers.
// ---------------------------------------------------------------------------

#define F 64
#define NGRAPHS 128
#define NCLASSES 10
#define FCAT 192
#define SPLIT 8
#define SCAN_CHUNK 512

// ---- preprocessing -------------------------------------------------------

__global__ void k_zero_int(int* __restrict__ p, int n) {
    int i = blockIdx.x * blockDim.x + threadIdx.x;
    if (i < n) p[i] = 0;
}
__global__ void k_zero_f(float* __restrict__ p, int n) {
    int i = blockIdx.x * blockDim.x + threadIdx.x;
    if (i < n) p[i] = 0.0f;
}

__global__ void k_count(const int* __restrict__ col, int* __restrict__ cnt, int E) {
    int e = blockIdx.x * blockDim.x + threadIdx.x;
    if (e < E) atomicAdd(&cnt[col[e]], 1);
}

// block sums of (cnt[i]+1) over chunks of 512
__global__ __launch_bounds__(256) void k_scan_block(const int* __restrict__ cnt, int n,
                                                    int* __restrict__ bsums) {
    __shared__ int red[256];
    int t = threadIdx.x;
    int base = blockIdx.x * SCAN_CHUNK;
    int i0 = base + 2 * t, i1 = i0 + 1;
    int v0 = (i0 < n) ? cnt[i0] + 1 : 0;
    int v1 = (i1 < n) ? cnt[i1] + 1 : 0;
    red[t] = v0 + v1;
    __syncthreads();
    for (int s = 128; s > 0; s >>= 1) {
        if (t < s) red[t] += red[t + s];
        __syncthreads();
    }
    if (t == 0) bsums[blockIdx.x] = red[0];
}

// serial exclusive scan of block sums (tiny); writes rowptr[n] = total
__global__ void k_scan_sums(int* __restrict__ bsums, int nb, int* __restrict__ rowptr, int n) {
    if (threadIdx.x == 0 && blockIdx.x == 0) {
        int acc = 0;
        for (int b = 0; b < nb; ++b) { int v = bsums[b]; bsums[b] = acc; acc += v; }
        rowptr[n] = acc;
    }
}

// local exclusive scan + block base -> rowptr
__global__ __launch_bounds__(256) void k_scan_write(const int* __restrict__ cnt, int n,
                                                    const int* __restrict__ bsums,
                                                    int* __restrict__ rowptr) {
    __shared__ int sc[256];
    int t = threadIdx.x;
    int base = blockIdx.x * SCAN_CHUNK;
    int i0 = base + 2 * t, i1 = i0 + 1;
    int v0 = (i0 < n) ? cnt[i0] + 1 : 0;
    int v1 = (i1 < n) ? cnt[i1] + 1 : 0;
    int pair = v0 + v1;
    sc[t] = pair;
    __syncthreads();
    for (int off = 1; off < 256; off <<= 1) {
        int val = (t >= off) ? sc[t - off] : 0;
        __syncthreads();
        sc[t] += val;
        __syncthreads();
    }
    int excl = sc[t] - pair;
    int bs = bsums[blockIdx.x];
    if (i0 < n) rowptr[i0] = bs + excl;
    if (i1 < n) rowptr[i1] = bs + excl + v0;
}

// dinv = rsqrt(deg); write self-loop CSR entry at slot 0; cnt becomes cursor=1
__global__ void k_self(int* __restrict__ cnt, float* __restrict__ dinv,
                       const int* __restrict__ rowptr, int2* __restrict__ meta, int n) {
    int i = blockIdx.x * blockDim.x + threadIdx.x;
    if (i >= n) return;
    int c = cnt[i];
    float d = rsqrtf((float)(c + 1));
    dinv[i] = d;
    meta[rowptr[i]] = make_int2(i, __float_as_int(d * d));
    cnt[i] = 1;  // cursor (slot 0 is self-loop)
}

// place each edge into its dest node's CSR segment
__global__ void k_fill(const int* __restrict__ row, const int* __restrict__ col,
                       const float* __restrict__ dinv, const int* __restrict__ rowptr,
                       int* __restrict__ cursor, int2* __restrict__ meta, int E) {
    int e = blockIdx.x * blockDim.x + threadIdx.x;
    if (e >= E) return;
    int r = row[e], c = col[e];
    int p = rowptr[c] + atomicAdd(&cursor[c], 1);
    meta[p] = make_int2(r, __float_as_int(dinv[r] * dinv[c]));
}

// ---- per-layer kernels ---------------------------------------------------

// xw = x @ W (one wave per row, W staged in LDS, float4 broadcast reads of x)
__global__ __launch_bounds__(256) void k_gemm(const float* __restrict__ x,
                                              const float* __restrict__ W,
                                              float* __restrict__ xw, int n) {
    __shared__ float Wl[F * F];
    for (int i = threadIdx.x; i < F * F; i += 256) Wl[i] = W[i];
    __syncthreads();
    int r = blockIdx.x * 4 + (threadIdx.x >> 6);
    if (r >= n) return;
    int f = threadIdx.x & 63;
    const float4* xr = (const float4*)(x + (size_t)r * F);
    float acc = 0.0f;
#pragma unroll
    for (int k = 0; k < 16; ++k) {
        float4 v = xr[k];
        acc = fmaf(v.x, Wl[(4 * k + 0) * F + f], acc);
        acc = fmaf(v.y, Wl[(4 * k + 1) * F + f], acc);
        acc = fmaf(v.z, Wl[(4 * k + 2) * F + f], acc);
        acc = fmaf(v.w, Wl[(4 * k + 3) * F + f], acc);
    }
    xw[(size_t)r * F + f] = acc;
}

// out[v] = relu( sum_{(r,w) in CSR[v]} xw[r]*w + b )
// one wave per node: 4 edge-groups x 16 lanes (float4 per lane)
__global__ __launch_bounds__(256) void k_gather(const float* __restrict__ xw,
                                                const int2* __restrict__ meta,
                                                const int* __restrict__ rowptr,
                                                const float* __restrict__ bias,
                                                float* __restrict__ out, int n) {
    int wid = (int)((blockIdx.x * blockDim.x + threadIdx.x) >> 6);
    if (wid >= n) return;
    int lane = threadIdx.x & 63;
    int g = lane >> 4, s = lane & 15;
    int start = rowptr[wid], end = rowptr[wid + 1];
    float ax = 0.0f, ay = 0.0f, az = 0.0f, aw = 0.0f;
    for (int i = start + g; i < end; i += 4) {
        int2 m = meta[i];
        float w = __int_as_float(m.y);
        const float4 xv = *(const float4*)(xw + ((size_t)m.x << 6) + (s << 2));
        ax = fmaf(xv.x, w, ax);
        ay = fmaf(xv.y, w, ay);
        az = fmaf(xv.z, w, az);
        aw = fmaf(xv.w, w, aw);
    }
#pragma unroll
    for (int m = 16; m <= 32; m <<= 1) {
        ax += __shfl_xor(ax, m);
        ay += __shfl_xor(ay, m);
        az += __shfl_xor(az, m);
        aw += __shfl_xor(aw, m);
    }
    if (g == 0) {
        float4 bv = ((const float4*)bias)[s];
        float4 o;
        o.x = fmaxf(ax + bv.x, 0.0f);
        o.y = fmaxf(ay + bv.y, 0.0f);
        o.z = fmaxf(az + bv.z, 0.0f);
        o.w = fmaxf(aw + bv.w, 0.0f);
        *(float4*)(out + ((size_t)wid << 6) + (s << 2)) = o;
    }
}

// partial pooled sums: grid = NGRAPHS*SPLIT blocks, 256 threads
__global__ __launch_bounds__(256) void k_pool_part(const float* __restrict__ x,
                                                   const int* __restrict__ batch, int n,
                                                   float* __restrict__ pooledSum,
                                                   int layerOff) {
    int g = blockIdx.x / SPLIT, part = blockIdx.x % SPLIT;
    int lo = 0, hi = n;
    while (lo < hi) { int m = (lo + hi) >> 1; if (batch[m] < g) lo = m + 1; else hi = m; }
    int s0 = lo;
    lo = s0; hi = n;
    while (lo < hi) { int m = (lo + hi) >> 1; if (batch[m] < g + 1) lo = m + 1; else hi = m; }
    int e0 = lo;
    int len = e0 - s0;
    int chunk = (len + SPLIT - 1) / SPLIT;
    int r0 = s0 + part * chunk;
    int r1 = min(r0 + chunk, e0);
    int f = threadIdx.x & 63, sub = threadIdx.x >> 6;
    float sum = 0.0f;
    for (int i = r0 + sub; i < r1; i += 4) sum += x[(size_t)i * F + f];
    atomicAdd(&pooledSum[g * FCAT + layerOff + f], sum);
}

// logits = (pooledSum/cnt) @ Wf + bf ; softmax
__global__ void k_head(const float* __restrict__ pooledSum, const int* __restrict__ batch,
                       int n, const float* __restrict__ Wf, const float* __restrict__ bf,
                       float* __restrict__ out) {
    int g = blockIdx.x * blockDim.x + threadIdx.x;
    if (g >= NGRAPHS) return;
    int lo = 0, hi = n;
    while (lo < hi) { int m = (lo + hi) >> 1; if (batch[m] < g) lo = m + 1; else hi = m; }
    int s0 = lo;
    lo = s0; hi = n;
    while (lo < hi) { int m = (lo + hi) >> 1; if (batch[m] < g + 1) lo = m + 1; else hi = m; }
    float invc = 1.0f / fmaxf((float)(lo - s0), 1.0f);
    float logit[NCLASSES];
#pragma unroll
    for (int c = 0; c < NCLASSES; ++c) logit[c] = bf[c];
    for (int k = 0; k < FCAT; ++k) {
        float p = pooledSum[g * FCAT + k] * invc;
#pragma unroll
        for (int c = 0; c < NCLASSES; ++c) logit[c] = fmaf(p, Wf[k * NCLASSES + c], logit[c]);
    }
    float mx = logit[0];
#pragma unroll
    for (int c = 1; c < NCLASSES; ++c) mx = fmaxf(mx, logit[c]);
    float ssum = 0.0f;
#pragma unroll
    for (int c = 0; c < NCLASSES; ++c) { logit[c] = expf(logit[c] - mx); ssum += logit[c]; }
    float inv = 1.0f / ssum;
#pragma unroll
    for (int c = 0; c < NCLASSES; ++c) out[g * NCLASSES + c] = logit[c] * inv;
}

// ---------------------------------------------------------------------------

extern "C" void kernel_launch(void* const* d_in, const int* in_sizes, int n_in,
                              void* d_out, int out_size, void* d_ws, size_t ws_size,
                              hipStream_t stream) {
    const float* features = (const float*)d_in[0];
    const int*   edge     = (const int*)d_in[1];
    const int*   batch    = (const int*)d_in[2];
    const float* W1 = (const float*)d_in[3]; const float* b1 = (const float*)d_in[4];
    const float* W2 = (const float*)d_in[5]; const float* b2 = (const float*)d_in[6];
    const float* W3 = (const float*)d_in[7]; const float* b3 = (const float*)d_in[8];
    const float* Wf = (const float*)d_in[9]; const float* bf = (const float*)d_in[10];
    float* out = (float*)d_out;

    const int n = in_sizes[0] / F;   // 100000
    const int E = in_sizes[1] / 2;   // 1600000
    const int* row = edge;
    const int* col = edge + E;

    const int NB = (n + SCAN_CHUNK - 1) / SCAN_CHUNK;

    // workspace layout (16B-aligned blocks first)
    float* bufA = (float*)d_ws;                       // [n*64]
    float* bufB = bufA + (size_t)n * F;               // [n*64]
    float* xw   = bufB + (size_t)n * F;               // [n*64]
    int2*  meta = (int2*)(xw + (size_t)n * F);        // [E+n]
    int*   cnt  = (int*)(meta + (size_t)E + n);       // [n] counts -> cursor
    float* dinv = (float*)(cnt + n);                  // [n]
    int*   rowptr = (int*)(dinv + n);                 // [n+1]
    int*   bsums  = rowptr + (n + 1);                 // [NB]
    float* pooledSum = (float*)(bsums + NB);          // [128*192]

    const int BT = 256;
    int gn  = (n + BT - 1) / BT;
    int gE  = (E + BT - 1) / BT;
    int gW  = (n + 3) / 4;       // gemm / gather grids (4 rows|nodes per block)

    // ---- CSR build ----
    k_zero_int<<<gn, BT, 0, stream>>>(cnt, n);
    k_zero_f<<<(NGRAPHS * FCAT + BT - 1) / BT, BT, 0, stream>>>(pooledSum, NGRAPHS * FCAT);
    k_count<<<gE, BT, 0, stream>>>(col, cnt, E);
    k_scan_block<<<NB, BT, 0, stream>>>(cnt, n, bsums);
    k_scan_sums<<<1, 64, 0, stream>>>(bsums, NB, rowptr, n);
    k_scan_write<<<NB, BT, 0, stream>>>(cnt, n, bsums, rowptr);
    k_self<<<gn, BT, 0, stream>>>(cnt, dinv, rowptr, meta, n);
    k_fill<<<gE, BT, 0, stream>>>(row, col, dinv, rowptr, cnt, meta, E);

    // ---- layer 1: features -> bufA ----
    k_gemm<<<gW, BT, 0, stream>>>(features, W1, xw, n);
    k_gather<<<gW, BT, 0, stream>>>(xw, meta, rowptr, b1, bufA, n);
    k_pool_part<<<NGRAPHS * SPLIT, BT, 0, stream>>>(bufA, batch, n, pooledSum, 0);

    // ---- layer 2: bufA -> bufB ----
    k_gemm<<<gW, BT, 0, stream>>>(bufA, W2, xw, n);
    k_gather<<<gW, BT, 0, stream>>>(xw, meta, rowptr, b2, bufB, n);
    k_pool_part<<<NGRAPHS * SPLIT, BT, 0, stream>>>(bufB, batch, n, pooledSum, F);

    // ---- layer 3: bufB -> bufA ----
    k_gemm<<<gW, BT, 0, stream>>>(bufB, W3, xw, n);
    k_gather<<<gW, BT, 0, stream>>>(xw, meta, rowptr, b3, bufA, n);
    k_pool_part<<<NGRAPHS * SPLIT, BT, 0, stream>>>(bufA, batch, n, pooledSum, 2 * F);

    // ---- head ----
    k_head<<<2, 64, 0, stream>>>(pooledSum, batch, n, Wf, bf, out);
}

// Round 3
// 566.451 us; speedup vs baseline: 2.8409x; 1.1442x over previous
//
#include <hip/hip_runtime.h>
#include <hip/hip_bf16.h>
#include <math.h>

// ---------------------------------------------------------------------------
// GCN 3-layer + mean-pool + linear head + softmax, fp32.
// CSR (by dest, self-loops inlined) built once per launch with slot-saving
// counting sort (no atomic round-trip in fill). Per layer: grid-stride GEMM
// (W staged once per block, 4-row register blocking) -> gather-aggregate
// (+bias+ReLU fused) -> split pooling.
// ---------------------------------------------------------------------------

#define F 64
#define NGRAPHS 128
#define NCLASSES 10
#define FCAT 192
#define SPLIT 8
#define SCAN_CHUNK 512
#define GEMM_BLOCKS 1024

// ---- preprocessing -------------------------------------------------------

__global__ void k_zero_int(int* __restrict__ p, int n) {
    int i = blockIdx.x * blockDim.x + threadIdx.x;
    if (i < n) p[i] = 0;
}
__global__ void k_zero_f(float* __restrict__ p, int n) {
    int i = blockIdx.x * blockDim.x + threadIdx.x;
    if (i < n) p[i] = 0.0f;
}

// slot[e] = position of edge e within its destination's segment
__global__ void k_count(const int* __restrict__ col, int* __restrict__ cnt,
                        int* __restrict__ slot, int E) {
    int e = blockIdx.x * blockDim.x + threadIdx.x;
    if (e < E) slot[e] = atomicAdd(&cnt[col[e]], 1);
}

// block sums of (cnt[i]+1) over chunks of 512
__global__ __launch_bounds__(256) void k_scan_block(const int* __restrict__ cnt, int n,
                                                    int* __restrict__ bsums) {
    __shared__ int red[256];
    int t = threadIdx.x;
    int base = blockIdx.x * SCAN_CHUNK;
    int i0 = base + 2 * t, i1 = i0 + 1;
    int v0 = (i0 < n) ? cnt[i0] + 1 : 0;
    int v1 = (i1 < n) ? cnt[i1] + 1 : 0;
    red[t] = v0 + v1;
    __syncthreads();
    for (int s = 128; s > 0; s >>= 1) {
        if (t < s) red[t] += red[t + s];
        __syncthreads();
    }
    if (t == 0) bsums[blockIdx.x] = red[0];
}

// serial exclusive scan of block sums (tiny); writes rowptr[n] = total
__global__ void k_scan_sums(int* __restrict__ bsums, int nb, int* __restrict__ rowptr, int n) {
    if (threadIdx.x == 0 && blockIdx.x == 0) {
        int acc = 0;
        for (int b = 0; b < nb; ++b) { int v = bsums[b]; bsums[b] = acc; acc += v; }
        rowptr[n] = acc;
    }
}

// local exclusive scan + block base -> rowptr
__global__ __launch_bounds__(256) void k_scan_write(const int* __restrict__ cnt, int n,
                                                    const int* __restrict__ bsums,
                                                    int* __restrict__ rowptr) {
    __shared__ int sc[256];
    int t = threadIdx.x;
    int base = blockIdx.x * SCAN_CHUNK;
    int i0 = base + 2 * t, i1 = i0 + 1;
    int v0 = (i0 < n) ? cnt[i0] + 1 : 0;
    int v1 = (i1 < n) ? cnt[i1] + 1 : 0;
    int pair = v0 + v1;
    sc[t] = pair;
    __syncthreads();
    for (int off = 1; off < 256; off <<= 1) {
        int val = (t >= off) ? sc[t - off] : 0;
        __syncthreads();
        sc[t] += val;
        __syncthreads();
    }
    int excl = sc[t] - pair;
    int bs = bsums[blockIdx.x];
    if (i0 < n) rowptr[i0] = bs + excl;
    if (i1 < n) rowptr[i1] = bs + excl + v0;
}

// dinv = rsqrt(deg); write self-loop CSR entry at slot 0
__global__ void k_self(const int* __restrict__ cnt, float* __restrict__ dinv,
                       const int* __restrict__ rowptr, int2* __restrict__ meta, int n) {
    int i = blockIdx.x * blockDim.x + threadIdx.x;
    if (i >= n) return;
    float d = rsqrtf((float)(cnt[i] + 1));
    dinv[i] = d;
    meta[rowptr[i]] = make_int2(i, __float_as_int(d * d));
}

// place each edge at its precomputed CSR position (no atomics)
__global__ void k_fill(const int* __restrict__ row, const int* __restrict__ col,
                       const int* __restrict__ slot, const float* __restrict__ dinv,
                       const int* __restrict__ rowptr, int2* __restrict__ meta, int E) {
    int e = blockIdx.x * blockDim.x + threadIdx.x;
    if (e >= E) return;
    int r = row[e], c = col[e];
    int p = rowptr[c] + 1 + slot[e];
    meta[p] = make_int2(r, __float_as_int(dinv[r] * dinv[c]));
}

// ---- per-layer kernels ---------------------------------------------------

// xw = x @ W. Grid-stride; W staged in LDS once per block; each wave handles
// 4 rows per iteration (1 LDS read amortized over 4 FMAs).
__global__ __launch_bounds__(256) void k_gemm(const float* __restrict__ x,
                                              const float* __restrict__ W,
                                              float* __restrict__ xw, int n) {
    __shared__ float Wl[F * F];
    for (int i = threadIdx.x; i < F * F; i += 256) Wl[i] = W[i];
    __syncthreads();
    int f = threadIdx.x & 63;
    int wave = threadIdx.x >> 6;             // 0..3
    int groups = (n + 3) >> 2;               // 4-row groups
    for (int gidx = blockIdx.x * 4 + wave; gidx < groups; gidx += gridDim.x * 4) {
        int r0 = gidx * 4;
        bool full = (r0 + 4 <= n);
        const float4* x0 = (const float4*)(x + (size_t)r0 * F);
        const float4* x1 = (const float4*)(x + (size_t)min(r0 + 1, n - 1) * F);
        const float4* x2 = (const float4*)(x + (size_t)min(r0 + 2, n - 1) * F);
        const float4* x3 = (const float4*)(x + (size_t)min(r0 + 3, n - 1) * F);
        float a0 = 0.f, a1 = 0.f, a2 = 0.f, a3 = 0.f;
#pragma unroll
        for (int k = 0; k < 16; ++k) {
            float4 v0 = x0[k], v1 = x1[k], v2 = x2[k], v3 = x3[k];
            float w;
            w = Wl[(4 * k + 0) * F + f];
            a0 = fmaf(v0.x, w, a0); a1 = fmaf(v1.x, w, a1);
            a2 = fmaf(v2.x, w, a2); a3 = fmaf(v3.x, w, a3);
            w = Wl[(4 * k + 1) * F + f];
            a0 = fmaf(v0.y, w, a0); a1 = fmaf(v1.y, w, a1);
            a2 = fmaf(v2.y, w, a2); a3 = fmaf(v3.y, w, a3);
            w = Wl[(4 * k + 2) * F + f];
            a0 = fmaf(v0.z, w, a0); a1 = fmaf(v1.z, w, a1);
            a2 = fmaf(v2.z, w, a2); a3 = fmaf(v3.z, w, a3);
            w = Wl[(4 * k + 3) * F + f];
            a0 = fmaf(v0.w, w, a0); a1 = fmaf(v1.w, w, a1);
            a2 = fmaf(v2.w, w, a2); a3 = fmaf(v3.w, w, a3);
        }
        float* o = xw + (size_t)r0 * F + f;
        if (full) {
            o[0] = a0; o[F] = a1; o[2 * F] = a2; o[3 * F] = a3;
        } else {
            o[0] = a0;
            if (r0 + 1 < n) o[F] = a1;
            if (r0 + 2 < n) o[2 * F] = a2;
            if (r0 + 3 < n) o[3 * F] = a3;
        }
    }
}

// out[v] = relu( sum_{(r,w) in CSR[v]} xw[r]*w + b )
// one wave per node: 4 edge-groups x 16 lanes (float4 per lane)
__global__ __launch_bounds__(256) void k_gather(const float* __restrict__ xw,
                                                const int2* __restrict__ meta,
                                                const int* __restrict__ rowptr,
                                                const float* __restrict__ bias,
                                                float* __restrict__ out, int n) {
    int wid = (int)((blockIdx.x * blockDim.x + threadIdx.x) >> 6);
    if (wid >= n) return;
    int lane = threadIdx.x & 63;
    int g = lane >> 4, s = lane & 15;
    int start = rowptr[wid], end = rowptr[wid + 1];
    float ax = 0.0f, ay = 0.0f, az = 0.0f, aw = 0.0f;
    for (int i = start + g; i < end; i += 4) {
        int2 m = meta[i];
        float w = __int_as_float(m.y);
        const float4 xv = *(const float4*)(xw + ((size_t)m.x << 6) + (s << 2));
        ax = fmaf(xv.x, w, ax);
        ay = fmaf(xv.y, w, ay);
        az = fmaf(xv.z, w, az);
        aw = fmaf(xv.w, w, aw);
    }
#pragma unroll
    for (int m = 16; m <= 32; m <<= 1) {
        ax += __shfl_xor(ax, m);
        ay += __shfl_xor(ay, m);
        az += __shfl_xor(az, m);
        aw += __shfl_xor(aw, m);
    }
    if (g == 0) {
        float4 bv = ((const float4*)bias)[s];
        float4 o;
        o.x = fmaxf(ax + bv.x, 0.0f);
        o.y = fmaxf(ay + bv.y, 0.0f);
        o.z = fmaxf(az + bv.z, 0.0f);
        o.w = fmaxf(aw + bv.w, 0.0f);
        *(float4*)(out + ((size_t)wid << 6) + (s << 2)) = o;
    }
}

// partial pooled sums: grid = NGRAPHS*SPLIT blocks, 256 threads
__global__ __launch_bounds__(256) void k_pool_part(const float* __restrict__ x,
                                                   const int* __restrict__ batch, int n,
                                                   float* __restrict__ pooledSum,
                                                   int layerOff) {
    int g = blockIdx.x / SPLIT, part = blockIdx.x % SPLIT;
    int lo = 0, hi = n;
    while (lo < hi) { int m = (lo + hi) >> 1; if (batch[m] < g) lo = m + 1; else hi = m; }
    int s0 = lo;
    lo = s0; hi = n;
    while (lo < hi) { int m = (lo + hi) >> 1; if (batch[m] < g + 1) lo = m + 1; else hi = m; }
    int e0 = lo;
    int len = e0 - s0;
    int chunk = (len + SPLIT - 1) / SPLIT;
    int r0 = s0 + part * chunk;
    int r1 = min(r0 + chunk, e0);
    int f = threadIdx.x & 63, sub = threadIdx.x >> 6;
    float sum = 0.0f;
    for (int i = r0 + sub; i < r1; i += 4) sum += x[(size_t)i * F + f];
    atomicAdd(&pooledSum[g * FCAT + layerOff + f], sum);
}

// logits = (pooledSum/cnt) @ Wf + bf ; softmax
__global__ void k_head(const float* __restrict__ pooledSum, const int* __restrict__ batch,
                       int n, const float* __restrict__ Wf, const float* __restrict__ bf,
                       float* __restrict__ out) {
    int g = blockIdx.x * blockDim.x + threadIdx.x;
    if (g >= NGRAPHS) return;
    int lo = 0, hi = n;
    while (lo < hi) { int m = (lo + hi) >> 1; if (batch[m] < g) lo = m + 1; else hi = m; }
    int s0 = lo;
    lo = s0; hi = n;
    while (lo < hi) { int m = (lo + hi) >> 1; if (batch[m] < g + 1) lo = m + 1; else hi = m; }
    float invc = 1.0f / fmaxf((float)(lo - s0), 1.0f);
    float logit[NCLASSES];
#pragma unroll
    for (int c = 0; c < NCLASSES; ++c) logit[c] = bf[c];
    for (int k = 0; k < FCAT; ++k) {
        float p = pooledSum[g * FCAT + k] * invc;
#pragma unroll
        for (int c = 0; c < NCLASSES; ++c) logit[c] = fmaf(p, Wf[k * NCLASSES + c], logit[c]);
    }
    float mx = logit[0];
#pragma unroll
    for (int c = 1; c < NCLASSES; ++c) mx = fmaxf(mx, logit[c]);
    float ssum = 0.0f;
#pragma unroll
    for (int c = 0; c < NCLASSES; ++c) { logit[c] = expf(logit[c] - mx); ssum += logit[c]; }
    float inv = 1.0f / ssum;
#pragma unroll
    for (int c = 0; c < NCLASSES; ++c) out[g * NCLASSES + c] = logit[c] * inv;
}

// ---------------------------------------------------------------------------

extern "C" void kernel_launch(void* const* d_in, const int* in_sizes, int n_in,
                              void* d_out, int out_size, void* d_ws, size_t ws_size,
                              hipStream_t stream) {
    const float* features = (const float*)d_in[0];
    const int*   edge     = (const int*)d_in[1];
    const int*   batch    = (const int*)d_in[2];
    const float* W1 = (const float*)d_in[3]; const float* b1 = (const float*)d_in[4];
    const float* W2 = (const float*)d_in[5]; const float* b2 = (const float*)d_in[6];
    const float* W3 = (const float*)d_in[7]; const float* b3 = (const float*)d_in[8];
    const float* Wf = (const float*)d_in[9]; const float* bf = (const float*)d_in[10];
    float* out = (float*)d_out;

    const int n = in_sizes[0] / F;   // 100000
    const int E = in_sizes[1] / 2;   // 1600000
    const int* row = edge;
    const int* col = edge + E;

    const int NB = (n + SCAN_CHUNK - 1) / SCAN_CHUNK;

    // workspace layout
    float* bufA = (float*)d_ws;                       // [n*64]
    float* bufB = bufA + (size_t)n * F;               // [n*64]
    float* xw   = bufB + (size_t)n * F;               // [n*64]
    int2*  meta = (int2*)(xw + (size_t)n * F);        // [E+n]
    int*   cnt  = (int*)(meta + (size_t)E + n);       // [n]
    float* dinv = (float*)(cnt + n);                  // [n]
    int*   rowptr = (int*)(dinv + n);                 // [n+1]
    int*   bsums  = rowptr + (n + 1);                 // [NB]
    float* pooledSum = (float*)(bsums + NB);          // [128*192]
    int*   slot = (int*)bufA;                         // [E] aliases bufA (CSR-build phase only)

    const int BT = 256;
    int gn  = (n + BT - 1) / BT;
    int gE  = (E + BT - 1) / BT;
    int gW  = (n + 3) / 4;       // gather grid (4 nodes per block)

    // ---- CSR build ----
    k_zero_int<<<gn, BT, 0, stream>>>(cnt, n);
    k_zero_f<<<(NGRAPHS * FCAT + BT - 1) / BT, BT, 0, stream>>>(pooledSum, NGRAPHS * FCAT);
    k_count<<<gE, BT, 0, stream>>>(col, cnt, slot, E);
    k_scan_block<<<NB, BT, 0, stream>>>(cnt, n, bsums);
    k_scan_sums<<<1, 64, 0, stream>>>(bsums, NB, rowptr, n);
    k_scan_write<<<NB, BT, 0, stream>>>(cnt, n, bsums, rowptr);
    k_self<<<gn, BT, 0, stream>>>(cnt, dinv, rowptr, meta, n);
    k_fill<<<gE, BT, 0, stream>>>(row, col, slot, dinv, rowptr, meta, E);

    // ---- layer 1: features -> bufA ----
    k_gemm<<<GEMM_BLOCKS, BT, 0, stream>>>(features, W1, xw, n);
    k_gather<<<gW, BT, 0, stream>>>(xw, meta, rowptr, b1, bufA, n);
    k_pool_part<<<NGRAPHS * SPLIT, BT, 0, stream>>>(bufA, batch, n, pooledSum, 0);

    // ---- layer 2: bufA -> bufB ----
    k_gemm<<<GEMM_BLOCKS, BT, 0, stream>>>(bufA, W2, xw, n);
    k_gather<<<gW, BT, 0, stream>>>(xw, meta, rowptr, b2, bufB, n);
    k_pool_part<<<NGRAPHS * SPLIT, BT, 0, stream>>>(bufB, batch, n, pooledSum, F);

    // ---- layer 3: bufB -> bufA ----
    k_gemm<<<GEMM_BLOCKS, BT, 0, stream>>>(bufB, W3, xw, n);
    k_gather<<<gW, BT, 0, stream>>>(xw, meta, rowptr, b3, bufA, n);
    k_pool_part<<<NGRAPHS * SPLIT, BT, 0, stream>>>(bufA, batch, n, pooledSum, 2 * F);

    // ---- head ----
    k_head<<<2, 64, 0, stream>>>(pooledSum, batch, n, Wf, bf, out);
}